// Round 1
// baseline (251.519 us; speedup 1.0000x reference)
//
#include <hip/hip_runtime.h>
#include <math.h>

// Problem constants
#define CC 384
#define DD 768
#define TT 32
#define NN 196
#define BB 16
#define KK 16
#define NSAMP 500
#define JV 18816          // N*C/4 (float4 groups per frame)
#define FRAME 75264       // N*C

__device__ __forceinline__ float gelu_exact(float x) {
    return 0.5f * x * (1.0f + erff(x * 0.70710678118654752440f));
}

// ---------------- Kernel 1: mean+max pool over N ----------------
// grid = B*T blocks, block = (96,4). Each block handles one (b,t) frame
// (contiguous 196*384 floats). xbar[row*768 + c] = mean, [.. + 384 + c] = max.
__global__ __launch_bounds__(384) void pool_kernel(const float* __restrict__ x,
                                                   float* __restrict__ xbar) {
    int row = blockIdx.x;                       // b*T + t
    const float4* xp = (const float4*)(x + (size_t)row * NN * CC);
    int tx = threadIdx.x;                       // 0..95 channel float4 group
    int ty = threadIdx.y;                       // 0..3
    float4 s = make_float4(0.f, 0.f, 0.f, 0.f);
    float4 m = make_float4(-INFINITY, -INFINITY, -INFINITY, -INFINITY);
    for (int n = ty; n < NN; n += 4) {
        float4 v = xp[n * 96 + tx];
        s.x += v.x; s.y += v.y; s.z += v.z; s.w += v.w;
        m.x = fmaxf(m.x, v.x); m.y = fmaxf(m.y, v.y);
        m.z = fmaxf(m.z, v.z); m.w = fmaxf(m.w, v.w);
    }
    __shared__ float4 ssum[4][96];
    __shared__ float4 smax[4][96];
    ssum[ty][tx] = s;
    smax[ty][tx] = m;
    __syncthreads();
    if (ty == 0) {
        for (int r = 1; r < 4; ++r) {
            float4 a = ssum[r][tx];
            s.x += a.x; s.y += a.y; s.z += a.z; s.w += a.w;
            float4 b = smax[r][tx];
            m.x = fmaxf(m.x, b.x); m.y = fmaxf(m.y, b.y);
            m.z = fmaxf(m.z, b.z); m.w = fmaxf(m.w, b.w);
        }
        const float inv = 1.0f / (float)NN;
        float* o = xbar + (size_t)row * DD;
        o[4*tx+0] = s.x * inv; o[4*tx+1] = s.y * inv;
        o[4*tx+2] = s.z * inv; o[4*tx+3] = s.w * inv;
        o[CC + 4*tx+0] = m.x; o[CC + 4*tx+1] = m.y;
        o[CC + 4*tx+2] = m.z; o[CC + 4*tx+3] = m.w;
    }
}

// ---------------- Kernel 2a: LayerNorm + FC_in (768->768) + GELU ----------------
// 4 rows per block, 256 threads (4 waves, one wave loads+LNs one row).
__global__ __launch_bounds__(256) void fcin_kernel(const float* __restrict__ xbar,
                                                   const float* __restrict__ ln_g,
                                                   const float* __restrict__ ln_b,
                                                   const float* __restrict__ w_in,
                                                   const float* __restrict__ b_in,
                                                   float* __restrict__ h1) {
    __shared__ float xs[4][DD];
    int tid = threadIdx.x;
    int wave = tid >> 6, lane = tid & 63;
    int row0 = blockIdx.x * 4;
    int row = row0 + wave;

    const float* xr = xbar + (size_t)row * DD;
    float lsum = 0.f, lsq = 0.f;
    #pragma unroll
    for (int i = lane; i < DD; i += 64) {
        float v = xr[i];
        xs[wave][i] = v;
        lsum += v; lsq += v * v;
    }
    #pragma unroll
    for (int off = 32; off; off >>= 1) {
        lsum += __shfl_down(lsum, off);
        lsq  += __shfl_down(lsq, off);
    }
    lsum = __shfl(lsum, 0);
    lsq  = __shfl(lsq, 0);
    float mean = lsum * (1.0f / DD);
    float var  = lsq * (1.0f / DD) - mean * mean;
    float inv  = rsqrtf(var + 1e-5f);
    #pragma unroll
    for (int i = lane; i < DD; i += 64)
        xs[wave][i] = (xs[wave][i] - mean) * inv * ln_g[i] + ln_b[i];
    __syncthreads();

    #pragma unroll
    for (int rr = 0; rr < 3; ++rr) {
        int col = tid + rr * 256;
        float a0 = b_in[col], a1 = a0, a2 = a0, a3 = a0;
        for (int i = 0; i < DD; ++i) {
            float wv = w_in[i * DD + col];
            a0 += xs[0][i] * wv;
            a1 += xs[1][i] * wv;
            a2 += xs[2][i] * wv;
            a3 += xs[3][i] * wv;
        }
        h1[(size_t)(row0 + 0) * DD + col] = gelu_exact(a0);
        h1[(size_t)(row0 + 1) * DD + col] = gelu_exact(a1);
        h1[(size_t)(row0 + 2) * DD + col] = gelu_exact(a2);
        h1[(size_t)(row0 + 3) * DD + col] = gelu_exact(a3);
    }
}

// ---------------- Kernel 2b: global mean over T of h1[..., 384:768] ----------------
__global__ __launch_bounds__(384) void gpool_kernel(const float* __restrict__ h1,
                                                    float* __restrict__ g) {
    int b = blockIdx.x, c = threadIdx.x;
    float s = 0.f;
    for (int t = 0; t < TT; ++t)
        s += h1[(size_t)(b * TT + t) * DD + CC + c];
    g[b * CC + c] = s * (1.0f / TT);
}

// ---------------- Kernel 2c: MLP (768->384->192->1) ----------------
// 4 rows per block, 384 threads.
__global__ __launch_bounds__(384) void mlp_kernel(const float* __restrict__ h1,
                                                  const float* __restrict__ g,
                                                  const float* __restrict__ w1,
                                                  const float* __restrict__ b1,
                                                  const float* __restrict__ w2,
                                                  const float* __restrict__ b2,
                                                  const float* __restrict__ w3,
                                                  const float* __restrict__ b3,
                                                  float* __restrict__ scores) {
    __shared__ float cat[4][DD];
    __shared__ float h2s[4][CC];
    __shared__ float h3s[4][192];
    int tid = threadIdx.x;
    int row0 = blockIdx.x * 4;
    int b = row0 >> 5;

    #pragma unroll
    for (int r = 0; r < 4; ++r) {
        cat[r][tid]      = h1[(size_t)(row0 + r) * DD + tid];  // local half
        cat[r][CC + tid] = g[b * CC + tid];                    // global half
    }
    __syncthreads();

    {   // h2 = gelu(cat @ w1 + b1), col = tid (0..383)
        float a0 = b1[tid], a1 = a0, a2 = a0, a3 = a0;
        for (int i = 0; i < DD; ++i) {
            float wv = w1[i * CC + tid];
            a0 += cat[0][i] * wv;
            a1 += cat[1][i] * wv;
            a2 += cat[2][i] * wv;
            a3 += cat[3][i] * wv;
        }
        h2s[0][tid] = gelu_exact(a0);
        h2s[1][tid] = gelu_exact(a1);
        h2s[2][tid] = gelu_exact(a2);
        h2s[3][tid] = gelu_exact(a3);
    }
    __syncthreads();

    if (tid < 192) {  // h3 = gelu(h2 @ w2 + b2)
        float a0 = b2[tid], a1 = a0, a2 = a0, a3 = a0;
        for (int i = 0; i < CC; ++i) {
            float wv = w2[i * 192 + tid];
            a0 += h2s[0][i] * wv;
            a1 += h2s[1][i] * wv;
            a2 += h2s[2][i] * wv;
            a3 += h2s[3][i] * wv;
        }
        float wt = w3[tid];
        h3s[0][tid] = gelu_exact(a0) * wt;
        h3s[1][tid] = gelu_exact(a1) * wt;
        h3s[2][tid] = gelu_exact(a2) * wt;
        h3s[3][tid] = gelu_exact(a3) * wt;
    }
    __syncthreads();

    if (tid < 4) {  // serial reduce per row (192 adds, trivial)
        float s = b3[0];
        for (int i = 0; i < 192; ++i) s += h3s[tid][i];
        scores[row0 + tid] = s;
    }
}

// ---------------- Kernel 3: min-max norm + perturbed top-k -> indicators ----------------
// grid = B blocks, 512 threads (500 samples active).
__global__ __launch_bounds__(512) void topk_kernel(const float* __restrict__ scores,
                                                   const float* __restrict__ noise,
                                                   float* __restrict__ ind) {
    __shared__ float ns[TT];
    __shared__ float mnmx[2];
    __shared__ int counts[KK * TT];
    int b = blockIdx.x, tid = threadIdx.x;

    if (tid < TT) ns[tid] = scores[b * TT + tid];
    counts[tid & 511] = 0;   // 512 threads cover 512 entries
    __syncthreads();
    if (tid == 0) {
        float mn = ns[0], mx = ns[0];
        for (int t = 1; t < TT; ++t) { mn = fminf(mn, ns[t]); mx = fmaxf(mx, ns[t]); }
        mnmx[0] = mn; mnmx[1] = mx;
    }
    __syncthreads();
    if (tid < TT) ns[tid] = (ns[tid] - mnmx[0]) / (mnmx[1] - mnmx[0] + 1e-5f);
    __syncthreads();

    if (tid < NSAMP) {
        const float* nb = noise + ((size_t)b * NSAMP + tid) * TT;
        float p[TT];
        #pragma unroll
        for (int t = 0; t < TT; ++t) p[t] = ns[t] + nb[t] * 0.05f;
        int k = 0;
        #pragma unroll
        for (int t = 0; t < TT; ++t) {
            int rank = 0;
            #pragma unroll
            for (int u = 0; u < TT; ++u)
                rank += (p[u] > p[t] || (p[u] == p[t] && u < t)) ? 1 : 0;
            if (rank < KK) { atomicAdd(&counts[k * TT + t], 1); ++k; }
        }
    }
    __syncthreads();
    ind[b * (KK * TT) + tid] = (float)counts[tid] * (1.0f / NSAMP);
}

// ---------------- Kernel 4: weighted gather out[b,k,j] = sum_t ind[b,k,t] * x[b,t,j] ----------------
// grid = (ceil(JV/256), B), block 256. Each thread: one float4 column j, all 16 k.
__global__ __launch_bounds__(256) void gather_kernel(const float* __restrict__ x,
                                                     const float* __restrict__ ind,
                                                     float* __restrict__ out) {
    __shared__ float w[KK * TT];
    int b = blockIdx.y;
    int tid = threadIdx.x;
    w[tid] = ind[b * (KK * TT) + tid];
    w[256 + tid] = ind[b * (KK * TT) + 256 + tid];
    __syncthreads();

    int j4 = blockIdx.x * 256 + tid;
    if (j4 >= JV) return;

    const float4* xb = (const float4*)(x + (size_t)b * TT * FRAME);
    float4 acc[KK];
    #pragma unroll
    for (int k = 0; k < KK; ++k) acc[k] = make_float4(0.f, 0.f, 0.f, 0.f);

    for (int t = 0; t < TT; ++t) {
        float4 v = xb[(size_t)t * JV + j4];
        #pragma unroll
        for (int k = 0; k < KK; ++k) {
            float wk = w[k * TT + t];
            acc[k].x += wk * v.x; acc[k].y += wk * v.y;
            acc[k].z += wk * v.z; acc[k].w += wk * v.w;
        }
    }
    float4* ob = (float4*)(out + (size_t)b * KK * FRAME);
    #pragma unroll
    for (int k = 0; k < KK; ++k)
        ob[(size_t)k * JV + j4] = acc[k];
}

extern "C" void kernel_launch(void* const* d_in, const int* in_sizes, int n_in,
                              void* d_out, int out_size, void* d_ws, size_t ws_size,
                              hipStream_t stream) {
    const float* x     = (const float*)d_in[0];
    const float* noise = (const float*)d_in[1];
    const float* ln_g  = (const float*)d_in[2];
    const float* ln_b  = (const float*)d_in[3];
    const float* w_in  = (const float*)d_in[4];
    const float* b_in  = (const float*)d_in[5];
    const float* w1    = (const float*)d_in[6];
    const float* b1    = (const float*)d_in[7];
    const float* w2    = (const float*)d_in[8];
    const float* b2    = (const float*)d_in[9];
    const float* w3    = (const float*)d_in[10];
    const float* b3    = (const float*)d_in[11];
    float* out = (float*)d_out;

    float* ws     = (float*)d_ws;
    float* xbar   = ws;                       // 512*768
    float* h1     = xbar + 512 * DD;          // 512*768
    float* g      = h1 + 512 * DD;            // 16*384
    float* scores = g + BB * CC;              // 512
    float* ind    = scores + 512;             // 16*512

    hipLaunchKernelGGL(pool_kernel, dim3(BB * TT), dim3(96, 4), 0, stream, x, xbar);
    hipLaunchKernelGGL(fcin_kernel, dim3(128), dim3(256), 0, stream,
                       xbar, ln_g, ln_b, w_in, b_in, h1);
    hipLaunchKernelGGL(gpool_kernel, dim3(BB), dim3(CC), 0, stream, h1, g);
    hipLaunchKernelGGL(mlp_kernel, dim3(128), dim3(CC), 0, stream,
                       h1, g, w1, b1, w2, b2, w3, b3, scores);
    hipLaunchKernelGGL(topk_kernel, dim3(BB), dim3(512), 0, stream, scores, noise, ind);
    hipLaunchKernelGGL(gather_kernel, dim3((JV + 255) / 256, BB), dim3(256), 0, stream,
                       x, ind, out);
}

// Round 2
// 172.686 us; speedup vs baseline: 1.4565x; 1.4565x over previous
//
#include <hip/hip_runtime.h>
#include <math.h>

// Problem constants
#define CC 384
#define DD 768
#define TT 32
#define NN 196
#define BB 16
#define KK 16
#define NSAMP 500
#define JV 18816          // N*C/4 (float4 groups per frame)
#define FRAME 75264       // N*C

__device__ __forceinline__ float gelu_exact(float x) {
    return 0.5f * x * (1.0f + erff(x * 0.70710678118654752440f));
}

// ---------------- Kernel 1: mean+max pool over N, fused LayerNorm ----------------
// grid = B*T blocks, block = (96,4). Each block handles one (b,t) frame.
// Writes xbar[row][0:768] ALREADY LayerNorm'd (so fcin is a pure GEMM).
__global__ __launch_bounds__(384) void pool_kernel(const float* __restrict__ x,
                                                   const float* __restrict__ ln_g,
                                                   const float* __restrict__ ln_b,
                                                   float* __restrict__ xbar) {
    int row = blockIdx.x;                       // b*T + t
    const float4* xp = (const float4*)(x + (size_t)row * NN * CC);
    int tx = threadIdx.x;                       // 0..95 channel float4 group
    int ty = threadIdx.y;                       // 0..3
    float4 s = make_float4(0.f, 0.f, 0.f, 0.f);
    float4 m = make_float4(-INFINITY, -INFINITY, -INFINITY, -INFINITY);
    for (int n = ty; n < NN; n += 4) {
        float4 v = xp[n * 96 + tx];
        s.x += v.x; s.y += v.y; s.z += v.z; s.w += v.w;
        m.x = fmaxf(m.x, v.x); m.y = fmaxf(m.y, v.y);
        m.z = fmaxf(m.z, v.z); m.w = fmaxf(m.w, v.w);
    }
    __shared__ float4 ssum[4][96];
    __shared__ float4 smax[4][96];
    __shared__ float xf[DD];
    ssum[ty][tx] = s;
    smax[ty][tx] = m;
    __syncthreads();
    if (ty == 0) {
        for (int r = 1; r < 4; ++r) {
            float4 a = ssum[r][tx];
            s.x += a.x; s.y += a.y; s.z += a.z; s.w += a.w;
            float4 b = smax[r][tx];
            m.x = fmaxf(m.x, b.x); m.y = fmaxf(m.y, b.y);
            m.z = fmaxf(m.z, b.z); m.w = fmaxf(m.w, b.w);
        }
        const float invn = 1.0f / (float)NN;
        xf[4*tx+0] = s.x * invn; xf[4*tx+1] = s.y * invn;
        xf[4*tx+2] = s.z * invn; xf[4*tx+3] = s.w * invn;
        xf[CC + 4*tx+0] = m.x; xf[CC + 4*tx+1] = m.y;
        xf[CC + 4*tx+2] = m.z; xf[CC + 4*tx+3] = m.w;
    }
    __syncthreads();
    // LayerNorm over the 768-vector: 384 threads, 2 elems each
    int tid = ty * 96 + tx;                     // 0..383
    float e0 = xf[tid], e1 = xf[tid + CC];
    float ps = e0 + e1, pq = e0 * e0 + e1 * e1;
    #pragma unroll
    for (int off = 32; off; off >>= 1) {
        ps += __shfl_down(ps, off);
        pq += __shfl_down(pq, off);
    }
    __shared__ float red[12];
    __shared__ float mv[2];
    int wv = tid >> 6;
    if ((tid & 63) == 0) { red[wv] = ps; red[6 + wv] = pq; }
    __syncthreads();
    if (tid == 0) {
        float su = 0.f, sq = 0.f;
        #pragma unroll
        for (int i = 0; i < 6; ++i) { su += red[i]; sq += red[6 + i]; }
        float mean = su * (1.0f / DD);
        float var  = sq * (1.0f / DD) - mean * mean;
        mv[0] = mean;
        mv[1] = rsqrtf(var + 1e-5f);
    }
    __syncthreads();
    float mean = mv[0], inv = mv[1];
    float* o = xbar + (size_t)row * DD;
    o[tid]      = (e0 - mean) * inv * ln_g[tid]      + ln_b[tid];
    o[tid + CC] = (e1 - mean) * inv * ln_g[tid + CC] + ln_b[tid + CC];
}

// ---------------- Kernel 2a: FC_in (768->768) + GELU (LN already applied) ----------------
// grid = (128 row-groups, 3 col-chunks), 256 threads. 4 rows, 1 col/thread.
__global__ __launch_bounds__(256) void fcin_kernel(const float* __restrict__ xbar,
                                                   const float* __restrict__ w_in,
                                                   const float* __restrict__ b_in,
                                                   float* __restrict__ h1) {
    __shared__ float xs[4][DD];
    int tid = threadIdx.x;
    int wave = tid >> 6, lane = tid & 63;
    int row0 = blockIdx.x * 4;
    {   // wave r stages row r (192 float4 per row)
        const float4* xr = (const float4*)(xbar + (size_t)(row0 + wave) * DD);
        float4* xd = (float4*)xs[wave];
        #pragma unroll
        for (int j = lane; j < DD / 4; j += 64) xd[j] = xr[j];
    }
    __syncthreads();

    int col = blockIdx.y * 256 + tid;
    float a0 = b_in[col], a1 = a0, a2 = a0, a3 = a0;
    const float* wp = w_in + col;
    #pragma unroll 2
    for (int i = 0; i < DD; i += 4) {
        float4 x0 = *(const float4*)&xs[0][i];
        float4 x1 = *(const float4*)&xs[1][i];
        float4 x2 = *(const float4*)&xs[2][i];
        float4 x3 = *(const float4*)&xs[3][i];
        float wv0 = wp[(i + 0) * DD];
        float wv1 = wp[(i + 1) * DD];
        float wv2 = wp[(i + 2) * DD];
        float wv3 = wp[(i + 3) * DD];
        a0 += x0.x * wv0 + x0.y * wv1 + x0.z * wv2 + x0.w * wv3;
        a1 += x1.x * wv0 + x1.y * wv1 + x1.z * wv2 + x1.w * wv3;
        a2 += x2.x * wv0 + x2.y * wv1 + x2.z * wv2 + x2.w * wv3;
        a3 += x3.x * wv0 + x3.y * wv1 + x3.z * wv2 + x3.w * wv3;
    }
    h1[(size_t)(row0 + 0) * DD + col] = gelu_exact(a0);
    h1[(size_t)(row0 + 1) * DD + col] = gelu_exact(a1);
    h1[(size_t)(row0 + 2) * DD + col] = gelu_exact(a2);
    h1[(size_t)(row0 + 3) * DD + col] = gelu_exact(a3);
}

// ---------------- Kernel 2b: global mean over T of h1[..., 384:768] ----------------
__global__ __launch_bounds__(384) void gpool_kernel(const float* __restrict__ h1,
                                                    float* __restrict__ g) {
    int b = blockIdx.x, c = threadIdx.x;
    float s = 0.f;
    #pragma unroll 8
    for (int t = 0; t < TT; ++t)
        s += h1[(size_t)(b * TT + t) * DD + CC + c];
    g[b * CC + c] = s * (1.0f / TT);
}

// ---------------- Kernel 2c: h2 = gelu(cat @ w1 + b1)  (768->384) ----------------
// grid = (128 row-groups, 2 col-chunks), 192 threads. 4 rows, 1 col/thread.
__global__ __launch_bounds__(192) void mlp1_kernel(const float* __restrict__ h1,
                                                   const float* __restrict__ g,
                                                   const float* __restrict__ w1,
                                                   const float* __restrict__ b1,
                                                   float* __restrict__ h2) {
    __shared__ float cat[4][DD];
    int tid = threadIdx.x;
    int row0 = blockIdx.x * 4;
    int b = row0 >> 5;
    // stage local halves (4 rows x 96 float4) and global half (replicated)
    for (int q = tid; q < 384; q += 192) {
        int r = q / 96, j = q % 96;
        ((float4*)cat[r])[j] = ((const float4*)(h1 + (size_t)(row0 + r) * DD))[j];
    }
    const float4* gb = (const float4*)(g + b * CC);
    for (int q = tid; q < 384; q += 192) {
        int r = q / 96, j = q % 96;
        ((float4*)cat[r])[96 + j] = gb[j];
    }
    __syncthreads();

    int col = blockIdx.y * 192 + tid;
    float a0 = b1[col], a1 = a0, a2 = a0, a3 = a0;
    const float* wp = w1 + col;
    #pragma unroll 2
    for (int i = 0; i < DD; i += 4) {
        float4 x0 = *(const float4*)&cat[0][i];
        float4 x1 = *(const float4*)&cat[1][i];
        float4 x2 = *(const float4*)&cat[2][i];
        float4 x3 = *(const float4*)&cat[3][i];
        float wv0 = wp[(i + 0) * CC];
        float wv1 = wp[(i + 1) * CC];
        float wv2 = wp[(i + 2) * CC];
        float wv3 = wp[(i + 3) * CC];
        a0 += x0.x * wv0 + x0.y * wv1 + x0.z * wv2 + x0.w * wv3;
        a1 += x1.x * wv0 + x1.y * wv1 + x1.z * wv2 + x1.w * wv3;
        a2 += x2.x * wv0 + x2.y * wv1 + x2.z * wv2 + x2.w * wv3;
        a3 += x3.x * wv0 + x3.y * wv1 + x3.z * wv2 + x3.w * wv3;
    }
    h2[(size_t)(row0 + 0) * CC + col] = gelu_exact(a0);
    h2[(size_t)(row0 + 1) * CC + col] = gelu_exact(a1);
    h2[(size_t)(row0 + 2) * CC + col] = gelu_exact(a2);
    h2[(size_t)(row0 + 3) * CC + col] = gelu_exact(a3);
}

// ---------------- Kernel 2d: h3 = gelu(h2 @ w2 + b2); scores = h3 @ w3 + b3 ----------------
// grid = 128 row-groups, 192 threads. 4 rows.
__global__ __launch_bounds__(192) void mlp2_kernel(const float* __restrict__ h2,
                                                   const float* __restrict__ w2,
                                                   const float* __restrict__ b2,
                                                   const float* __restrict__ w3,
                                                   const float* __restrict__ b3,
                                                   float* __restrict__ scores) {
    __shared__ float h2s[4][CC];
    __shared__ float h3s[4][192];
    int tid = threadIdx.x;
    int row0 = blockIdx.x * 4;
    for (int q = tid; q < 384; q += 192) {
        int r = q / 96, j = q % 96;
        ((float4*)h2s[r])[j] = ((const float4*)(h2 + (size_t)(row0 + r) * CC))[j];
    }
    __syncthreads();

    {   // col = tid (0..191)
        float a0 = b2[tid], a1 = a0, a2 = a0, a3 = a0;
        const float* wp = w2 + tid;
        #pragma unroll 2
        for (int i = 0; i < CC; i += 4) {
            float4 x0 = *(const float4*)&h2s[0][i];
            float4 x1 = *(const float4*)&h2s[1][i];
            float4 x2 = *(const float4*)&h2s[2][i];
            float4 x3 = *(const float4*)&h2s[3][i];
            float wv0 = wp[(i + 0) * 192];
            float wv1 = wp[(i + 1) * 192];
            float wv2 = wp[(i + 2) * 192];
            float wv3 = wp[(i + 3) * 192];
            a0 += x0.x * wv0 + x0.y * wv1 + x0.z * wv2 + x0.w * wv3;
            a1 += x1.x * wv0 + x1.y * wv1 + x1.z * wv2 + x1.w * wv3;
            a2 += x2.x * wv0 + x2.y * wv1 + x2.z * wv2 + x2.w * wv3;
            a3 += x3.x * wv0 + x3.y * wv1 + x3.z * wv2 + x3.w * wv3;
        }
        float wt = w3[tid];
        h3s[0][tid] = gelu_exact(a0) * wt;
        h3s[1][tid] = gelu_exact(a1) * wt;
        h3s[2][tid] = gelu_exact(a2) * wt;
        h3s[3][tid] = gelu_exact(a3) * wt;
    }
    __syncthreads();

    if (tid < 4) {
        float s = b3[0];
        #pragma unroll 8
        for (int i = 0; i < 192; ++i) s += h3s[tid][i];
        scores[row0 + tid] = s;
    }
}

// ---------------- Kernel 3: min-max norm + perturbed top-k -> indicators ----------------
__global__ __launch_bounds__(512) void topk_kernel(const float* __restrict__ scores,
                                                   const float* __restrict__ noise,
                                                   float* __restrict__ ind) {
    __shared__ float ns[TT];
    __shared__ float mnmx[2];
    __shared__ int counts[KK * TT];
    int b = blockIdx.x, tid = threadIdx.x;

    if (tid < TT) ns[tid] = scores[b * TT + tid];
    counts[tid & 511] = 0;
    __syncthreads();
    if (tid == 0) {
        float mn = ns[0], mx = ns[0];
        for (int t = 1; t < TT; ++t) { mn = fminf(mn, ns[t]); mx = fmaxf(mx, ns[t]); }
        mnmx[0] = mn; mnmx[1] = mx;
    }
    __syncthreads();
    if (tid < TT) ns[tid] = (ns[tid] - mnmx[0]) / (mnmx[1] - mnmx[0] + 1e-5f);
    __syncthreads();

    if (tid < NSAMP) {
        const float* nb = noise + ((size_t)b * NSAMP + tid) * TT;
        float p[TT];
        #pragma unroll
        for (int t = 0; t < TT; ++t) p[t] = ns[t] + nb[t] * 0.05f;
        int k = 0;
        #pragma unroll
        for (int t = 0; t < TT; ++t) {
            int rank = 0;
            #pragma unroll
            for (int u = 0; u < TT; ++u)
                rank += (p[u] > p[t] || (p[u] == p[t] && u < t)) ? 1 : 0;
            if (rank < KK) { atomicAdd(&counts[k * TT + t], 1); ++k; }
        }
    }
    __syncthreads();
    ind[b * (KK * TT) + tid] = (float)counts[tid] * (1.0f / NSAMP);
}

// ---------------- Kernel 4: weighted gather ----------------
__global__ __launch_bounds__(256) void gather_kernel(const float* __restrict__ x,
                                                     const float* __restrict__ ind,
                                                     float* __restrict__ out) {
    __shared__ float w[KK * TT];
    int b = blockIdx.y;
    int tid = threadIdx.x;
    w[tid] = ind[b * (KK * TT) + tid];
    w[256 + tid] = ind[b * (KK * TT) + 256 + tid];
    __syncthreads();

    int j4 = blockIdx.x * 256 + tid;
    if (j4 >= JV) return;

    const float4* xb = (const float4*)(x + (size_t)b * TT * FRAME);
    float4 acc[KK];
    #pragma unroll
    for (int k = 0; k < KK; ++k) acc[k] = make_float4(0.f, 0.f, 0.f, 0.f);

    for (int t = 0; t < TT; ++t) {
        float4 v = xb[(size_t)t * JV + j4];
        #pragma unroll
        for (int k = 0; k < KK; ++k) {
            float wk = w[k * TT + t];
            acc[k].x += wk * v.x; acc[k].y += wk * v.y;
            acc[k].z += wk * v.z; acc[k].w += wk * v.w;
        }
    }
    float4* ob = (float4*)(out + (size_t)b * KK * FRAME);
    #pragma unroll
    for (int k = 0; k < KK; ++k)
        ob[(size_t)k * JV + j4] = acc[k];
}

extern "C" void kernel_launch(void* const* d_in, const int* in_sizes, int n_in,
                              void* d_out, int out_size, void* d_ws, size_t ws_size,
                              hipStream_t stream) {
    const float* x     = (const float*)d_in[0];
    const float* noise = (const float*)d_in[1];
    const float* ln_g  = (const float*)d_in[2];
    const float* ln_b  = (const float*)d_in[3];
    const float* w_in  = (const float*)d_in[4];
    const float* b_in  = (const float*)d_in[5];
    const float* w1    = (const float*)d_in[6];
    const float* b1    = (const float*)d_in[7];
    const float* w2    = (const float*)d_in[8];
    const float* b2    = (const float*)d_in[9];
    const float* w3    = (const float*)d_in[10];
    const float* b3    = (const float*)d_in[11];
    float* out = (float*)d_out;

    float* ws     = (float*)d_ws;
    float* xbar   = ws;                       // 512*768 (LayerNorm'd)
    float* h1     = xbar + 512 * DD;          // 512*768
    float* g      = h1 + 512 * DD;            // 16*384
    float* scores = g + BB * CC;              // 512
    float* ind    = scores + 512;             // 16*512
    float* h2     = ind + BB * KK * TT;       // 512*384

    hipLaunchKernelGGL(pool_kernel, dim3(BB * TT), dim3(96, 4), 0, stream,
                       x, ln_g, ln_b, xbar);
    hipLaunchKernelGGL(fcin_kernel, dim3(128, 3), dim3(256), 0, stream,
                       xbar, w_in, b_in, h1);
    hipLaunchKernelGGL(gpool_kernel, dim3(BB), dim3(CC), 0, stream, h1, g);
    hipLaunchKernelGGL(mlp1_kernel, dim3(128, 2), dim3(192), 0, stream,
                       h1, g, w1, b1, h2);
    hipLaunchKernelGGL(mlp2_kernel, dim3(128), dim3(192), 0, stream,
                       h2, w2, b2, w3, b3, scores);
    hipLaunchKernelGGL(topk_kernel, dim3(BB), dim3(512), 0, stream, scores, noise, ind);
    hipLaunchKernelGGL(gather_kernel, dim3((JV + 255) / 256, BB), dim3(256), 0, stream,
                       x, ind, out);
}

// Round 3
// 168.834 us; speedup vs baseline: 1.4897x; 1.0228x over previous
//
#include <hip/hip_runtime.h>
#include <math.h>

// Problem constants
#define CC 384
#define DD 768
#define TT 32
#define NN 196
#define BB 16
#define KK 16
#define NSAMP 500
#define JV 18816          // N*C/4 (float4 groups per frame)
#define FRAME 75264       // N*C

__device__ __forceinline__ float gelu_exact(float x) {
    return 0.5f * x * (1.0f + erff(x * 0.70710678118654752440f));
}

// ---------------- Kernel 1: mean+max pool over N, fused LayerNorm ----------------
// grid = B*T blocks, block = (96,4). Writes xbar[row][0:768] already LayerNorm'd.
__global__ __launch_bounds__(384) void pool_kernel(const float* __restrict__ x,
                                                   const float* __restrict__ ln_g,
                                                   const float* __restrict__ ln_b,
                                                   float* __restrict__ xbar) {
    int row = blockIdx.x;                       // b*T + t
    const float4* xp = (const float4*)(x + (size_t)row * NN * CC);
    int tx = threadIdx.x;                       // 0..95 channel float4 group
    int ty = threadIdx.y;                       // 0..3
    float4 s = make_float4(0.f, 0.f, 0.f, 0.f);
    float4 m = make_float4(-INFINITY, -INFINITY, -INFINITY, -INFINITY);
    for (int n = ty; n < NN; n += 4) {
        float4 v = xp[n * 96 + tx];
        s.x += v.x; s.y += v.y; s.z += v.z; s.w += v.w;
        m.x = fmaxf(m.x, v.x); m.y = fmaxf(m.y, v.y);
        m.z = fmaxf(m.z, v.z); m.w = fmaxf(m.w, v.w);
    }
    __shared__ float4 ssum[4][96];
    __shared__ float4 smax[4][96];
    __shared__ float xf[DD];
    ssum[ty][tx] = s;
    smax[ty][tx] = m;
    __syncthreads();
    if (ty == 0) {
        for (int r = 1; r < 4; ++r) {
            float4 a = ssum[r][tx];
            s.x += a.x; s.y += a.y; s.z += a.z; s.w += a.w;
            float4 b = smax[r][tx];
            m.x = fmaxf(m.x, b.x); m.y = fmaxf(m.y, b.y);
            m.z = fmaxf(m.z, b.z); m.w = fmaxf(m.w, b.w);
        }
        const float invn = 1.0f / (float)NN;
        xf[4*tx+0] = s.x * invn; xf[4*tx+1] = s.y * invn;
        xf[4*tx+2] = s.z * invn; xf[4*tx+3] = s.w * invn;
        xf[CC + 4*tx+0] = m.x; xf[CC + 4*tx+1] = m.y;
        xf[CC + 4*tx+2] = m.z; xf[CC + 4*tx+3] = m.w;
    }
    __syncthreads();
    int tid = ty * 96 + tx;                     // 0..383
    float e0 = xf[tid], e1 = xf[tid + CC];
    float ps = e0 + e1, pq = e0 * e0 + e1 * e1;
    #pragma unroll
    for (int off = 32; off; off >>= 1) {
        ps += __shfl_down(ps, off);
        pq += __shfl_down(pq, off);
    }
    __shared__ float red[12];
    __shared__ float mv[2];
    int wv = tid >> 6;
    if ((tid & 63) == 0) { red[wv] = ps; red[6 + wv] = pq; }
    __syncthreads();
    if (tid == 0) {
        float su = 0.f, sq = 0.f;
        #pragma unroll
        for (int i = 0; i < 6; ++i) { su += red[i]; sq += red[6 + i]; }
        float mean = su * (1.0f / DD);
        float var  = sq * (1.0f / DD) - mean * mean;
        mv[0] = mean;
        mv[1] = rsqrtf(var + 1e-5f);
    }
    __syncthreads();
    float mean = mv[0], inv = mv[1];
    float* o = xbar + (size_t)row * DD;
    o[tid]      = (e0 - mean) * inv * ln_g[tid]      + ln_b[tid];
    o[tid + CC] = (e1 - mean) * inv * ln_g[tid + CC] + ln_b[tid + CC];
}

// ---------------- Kernel 2a: FC_in partial GEMM (split-K=2), x via scalar loads ----------------
// grid = (128 rowg, 3 colg, 2 kc), 256 threads. 4 rows x 256 cols, K=384 per chunk.
__global__ __launch_bounds__(256) void fcinA_kernel(const float* __restrict__ xbar,
                                                    const float* __restrict__ w_in,
                                                    float* __restrict__ pfc) {
    int tid = threadIdx.x;
    int row0 = blockIdx.x * 4;
    int col  = blockIdx.y * 256 + tid;
    int k0   = blockIdx.z * 384;
    const float* xr = xbar + (size_t)row0 * DD;   // wave-uniform -> scalar loads
    const float* wp = w_in + col;
    float a0 = 0.f, a1 = 0.f, a2 = 0.f, a3 = 0.f;
    #pragma unroll 4
    for (int i = k0; i < k0 + 384; ++i) {
        float wv = wp[(size_t)i * DD];
        a0 += xr[i]          * wv;
        a1 += xr[DD + i]     * wv;
        a2 += xr[2 * DD + i] * wv;
        a3 += xr[3 * DD + i] * wv;
    }
    float* o = pfc + (size_t)blockIdx.z * 512 * DD + (size_t)row0 * DD + col;
    o[0] = a0; o[DD] = a1; o[2 * DD] = a2; o[3 * DD] = a3;
}

// ---------------- Kernel 2b: combine partials + bias + GELU -> h1 ----------------
__global__ __launch_bounds__(192) void fcinB_kernel(const float* __restrict__ pfc,
                                                    const float* __restrict__ b_in,
                                                    float* __restrict__ h1) {
    int row = blockIdx.x, tid = threadIdx.x;      // 192 float4 = 768
    const float4* p0 = (const float4*)(pfc + (size_t)row * DD);
    const float4* p1 = (const float4*)(pfc + (size_t)512 * DD + (size_t)row * DD);
    const float4* bb = (const float4*)b_in;
    float4 u = p0[tid], v = p1[tid], b = bb[tid];
    float4 r;
    r.x = gelu_exact(u.x + v.x + b.x);
    r.y = gelu_exact(u.y + v.y + b.y);
    r.z = gelu_exact(u.z + v.z + b.z);
    r.w = gelu_exact(u.w + v.w + b.w);
    ((float4*)(h1 + (size_t)row * DD))[tid] = r;
}

// ---------------- Kernel 2c: global mean over T of h1[..., 384:768] ----------------
__global__ __launch_bounds__(64) void gpool_kernel(const float* __restrict__ h1,
                                                   float* __restrict__ g) {
    int b = blockIdx.x;
    int c = blockIdx.y * 64 + threadIdx.x;
    float s = 0.f;
    #pragma unroll 8
    for (int t = 0; t < TT; ++t)
        s += h1[(size_t)(b * TT + t) * DD + CC + c];
    g[b * CC + c] = s * (1.0f / TT);
}

// ---------------- Kernel 2d: mlp1 partial GEMM (split-K=2) ----------------
// grid = (128 rowg, 2 colg, 2 kc), 192 threads. kc=0: local half, kc=1: global half.
__global__ __launch_bounds__(192) void mlp1A_kernel(const float* __restrict__ h1,
                                                    const float* __restrict__ g,
                                                    const float* __restrict__ w1,
                                                    float* __restrict__ pm1) {
    int tid = threadIdx.x;
    int row0 = blockIdx.x * 4;
    int col  = blockIdx.y * 192 + tid;
    float a0 = 0.f, a1 = 0.f, a2 = 0.f, a3 = 0.f;
    const float* wp = w1 + col;
    if (blockIdx.z == 0) {
        const float* xr = h1 + (size_t)row0 * DD;
        #pragma unroll 4
        for (int i = 0; i < 384; ++i) {
            float wv = wp[(size_t)i * CC];
            a0 += xr[i]          * wv;
            a1 += xr[DD + i]     * wv;
            a2 += xr[2 * DD + i] * wv;
            a3 += xr[3 * DD + i] * wv;
        }
    } else {
        const float* gp = g + (row0 >> 5) * CC;   // same for all 4 rows
        float a = 0.f;
        #pragma unroll 4
        for (int i = 0; i < 384; ++i) {
            float wv = wp[(size_t)(384 + i) * CC];
            a += gp[i] * wv;
        }
        a0 = a1 = a2 = a3 = a;
    }
    float* o = pm1 + (size_t)blockIdx.z * 512 * CC + (size_t)row0 * CC + col;
    o[0] = a0; o[CC] = a1; o[2 * CC] = a2; o[3 * CC] = a3;
}

// ---------------- Kernel 2e: combine + bias + GELU -> h2 ----------------
__global__ __launch_bounds__(192) void mlp1B_kernel(const float* __restrict__ pm1,
                                                    const float* __restrict__ b1,
                                                    float* __restrict__ h2) {
    int row = blockIdx.x, tid = threadIdx.x;      // 192 float2 = 384
    const float2* p0 = (const float2*)(pm1 + (size_t)row * CC);
    const float2* p1 = (const float2*)(pm1 + (size_t)512 * CC + (size_t)row * CC);
    const float2* bb = (const float2*)b1;
    float2 u = p0[tid], v = p1[tid], b = bb[tid];
    float2 r;
    r.x = gelu_exact(u.x + v.x + b.x);
    r.y = gelu_exact(u.y + v.y + b.y);
    ((float2*)(h2 + (size_t)row * CC))[tid] = r;
}

// ---------------- Kernel 2f: mlp2 (384->192, GELU, x w3, reduce) -> scores ----------------
// grid = 512 (one row per block), 192 threads.
__global__ __launch_bounds__(192) void mlp2_kernel(const float* __restrict__ h2,
                                                   const float* __restrict__ w2,
                                                   const float* __restrict__ b2,
                                                   const float* __restrict__ w3,
                                                   const float* __restrict__ b3,
                                                   float* __restrict__ scores) {
    int row = blockIdx.x, tid = threadIdx.x;
    const float* hr = h2 + (size_t)row * CC;      // wave-uniform -> scalar loads
    const float* wp = w2 + tid;
    float a = b2[tid];
    #pragma unroll 4
    for (int i = 0; i < CC; ++i)
        a += hr[i] * wp[(size_t)i * 192];
    float v = gelu_exact(a) * w3[tid];
    #pragma unroll
    for (int off = 32; off; off >>= 1) v += __shfl_down(v, off);
    __shared__ float red[3];
    if ((tid & 63) == 0) red[tid >> 6] = v;
    __syncthreads();
    if (tid == 0) scores[row] = red[0] + red[1] + red[2] + b3[0];
}

// ---------------- Kernel 3: min-max norm + perturbed top-k -> indicators ----------------
__global__ __launch_bounds__(512) void topk_kernel(const float* __restrict__ scores,
                                                   const float* __restrict__ noise,
                                                   float* __restrict__ ind) {
    __shared__ float ns[TT];
    __shared__ float mnmx[2];
    __shared__ int counts[KK * TT];
    int b = blockIdx.x, tid = threadIdx.x;

    if (tid < TT) ns[tid] = scores[b * TT + tid];
    counts[tid & 511] = 0;
    __syncthreads();
    if (tid == 0) {
        float mn = ns[0], mx = ns[0];
        for (int t = 1; t < TT; ++t) { mn = fminf(mn, ns[t]); mx = fmaxf(mx, ns[t]); }
        mnmx[0] = mn; mnmx[1] = mx;
    }
    __syncthreads();
    if (tid < TT) ns[tid] = (ns[tid] - mnmx[0]) / (mnmx[1] - mnmx[0] + 1e-5f);
    __syncthreads();

    if (tid < NSAMP) {
        const float* nb = noise + ((size_t)b * NSAMP + tid) * TT;
        float p[TT];
        #pragma unroll
        for (int t = 0; t < TT; ++t) p[t] = ns[t] + nb[t] * 0.05f;
        int k = 0;
        #pragma unroll
        for (int t = 0; t < TT; ++t) {
            int rank = 0;
            #pragma unroll
            for (int u = 0; u < TT; ++u)
                rank += (p[u] > p[t] || (p[u] == p[t] && u < t)) ? 1 : 0;
            if (rank < KK) { atomicAdd(&counts[k * TT + t], 1); ++k; }
        }
    }
    __syncthreads();
    ind[b * (KK * TT) + tid] = (float)counts[tid] * (1.0f / NSAMP);
}

// ---------------- Kernel 4: weighted gather with zero-frame skip ----------------
__global__ __launch_bounds__(256) void gather_kernel(const float* __restrict__ x,
                                                     const float* __restrict__ ind,
                                                     float* __restrict__ out) {
    __shared__ float w[KK * TT];
    __shared__ int flag[TT];
    int b = blockIdx.y;
    int tid = threadIdx.x;
    w[tid] = ind[b * (KK * TT) + tid];
    w[256 + tid] = ind[b * (KK * TT) + 256 + tid];
    __syncthreads();
    if (tid < TT) {
        float s = 0.f;
        #pragma unroll
        for (int k = 0; k < KK; ++k) s += fabsf(w[k * TT + tid]);
        flag[tid] = (s != 0.f);
    }
    __syncthreads();

    int j4 = blockIdx.x * 256 + tid;
    if (j4 >= JV) return;

    const float4* xb = (const float4*)(x + (size_t)b * TT * FRAME);
    float4 acc[KK];
    #pragma unroll
    for (int k = 0; k < KK; ++k) acc[k] = make_float4(0.f, 0.f, 0.f, 0.f);

    for (int t = 0; t < TT; ++t) {
        if (!flag[t]) continue;                   // block-uniform branch
        float4 v = xb[(size_t)t * JV + j4];
        #pragma unroll
        for (int k = 0; k < KK; ++k) {
            float wk = w[k * TT + t];
            acc[k].x += wk * v.x; acc[k].y += wk * v.y;
            acc[k].z += wk * v.z; acc[k].w += wk * v.w;
        }
    }
    float4* ob = (float4*)(out + (size_t)b * KK * FRAME);
    #pragma unroll
    for (int k = 0; k < KK; ++k)
        ob[(size_t)k * JV + j4] = acc[k];
}

extern "C" void kernel_launch(void* const* d_in, const int* in_sizes, int n_in,
                              void* d_out, int out_size, void* d_ws, size_t ws_size,
                              hipStream_t stream) {
    const float* x     = (const float*)d_in[0];
    const float* noise = (const float*)d_in[1];
    const float* ln_g  = (const float*)d_in[2];
    const float* ln_b  = (const float*)d_in[3];
    const float* w_in  = (const float*)d_in[4];
    const float* b_in  = (const float*)d_in[5];
    const float* w1    = (const float*)d_in[6];
    const float* b1    = (const float*)d_in[7];
    const float* w2    = (const float*)d_in[8];
    const float* b2    = (const float*)d_in[9];
    const float* w3    = (const float*)d_in[10];
    const float* b3    = (const float*)d_in[11];
    float* out = (float*)d_out;

    float* ws     = (float*)d_ws;
    float* xbar   = ws;                       // 512*768 (LayerNorm'd)
    float* h1     = xbar + 512 * DD;          // 512*768
    float* g      = h1 + 512 * DD;            // 16*384
    float* scores = g + BB * CC;              // 512
    float* ind    = scores + 512;             // 16*512
    float* h2     = ind + BB * KK * TT;       // 512*384
    float* pfc    = h2 + 512 * CC;            // 2*512*768
    float* pm1    = pfc + 2 * 512 * DD;       // 2*512*384

    hipLaunchKernelGGL(pool_kernel, dim3(BB * TT), dim3(96, 4), 0, stream,
                       x, ln_g, ln_b, xbar);
    hipLaunchKernelGGL(fcinA_kernel, dim3(128, 3, 2), dim3(256), 0, stream,
                       xbar, w_in, pfc);
    hipLaunchKernelGGL(fcinB_kernel, dim3(512), dim3(192), 0, stream,
                       pfc, b_in, h1);
    hipLaunchKernelGGL(gpool_kernel, dim3(BB, 6), dim3(64), 0, stream, h1, g);
    hipLaunchKernelGGL(mlp1A_kernel, dim3(128, 2, 2), dim3(192), 0, stream,
                       h1, g, w1, pm1);
    hipLaunchKernelGGL(mlp1B_kernel, dim3(512), dim3(192), 0, stream,
                       pm1, b1, h2);
    hipLaunchKernelGGL(mlp2_kernel, dim3(512), dim3(192), 0, stream,
                       h2, w2, b2, w3, b3, scores);
    hipLaunchKernelGGL(topk_kernel, dim3(BB), dim3(512), 0, stream, scores, noise, ind);
    hipLaunchKernelGGL(gather_kernel, dim3((JV + 255) / 256, BB), dim3(256), 0, stream,
                       x, ind, out);
}